// Round 1
// baseline (426.549 us; speedup 1.0000x reference)
//
#include <hip/hip_runtime.h>
#include <hip/hip_bf16.h>

typedef float f32x4 __attribute__((ext_vector_type(4)));
typedef short s16x8 __attribute__((ext_vector_type(8)));

__device__ __forceinline__ unsigned short f2bf(float f) {
    union { float f; unsigned u; } v; v.f = f;
    unsigned r = v.u + 0x7FFF + ((v.u >> 16) & 1);   // RNE
    return (unsigned short)(r >> 16);
}

// ---------------------------------------------------------------------------
// Kernel 0: convert W [1024][64] fp32 -> W_t [192][1024] bf16 (transposed).
// cols 0..63 = Wq (prescaled by 0.125 = H^-0.5), 64..127 = Wk, 128..191 = Wv
// ---------------------------------------------------------------------------
__global__ void prep_w(const float* __restrict__ Wk, const float* __restrict__ Wq,
                       const float* __restrict__ Wv, unsigned short* __restrict__ wt) {
    int n = blockIdx.x;          // 0..191
    int tid = threadIdx.x;       // 0..255
    const float* src; int col; float sc = 1.0f;
    if (n < 64)       { src = Wq; col = n;       sc = 0.125f; }
    else if (n < 128) { src = Wk; col = n - 64; }
    else              { src = Wv; col = n - 128; }
#pragma unroll
    for (int i = 0; i < 4; i++) {
        int c = i * 256 + tid;
        wt[n * 1024 + c] = f2bf(src[c * 64 + col] * sc);
    }
}

// ---------------------------------------------------------------------------
// Kernel 1: qkv[65536][192] bf16 = x[65536][1024] fp32  @  W_t^T
// block tile 128(M) x 192(N), BK=64, 4 waves of 64x96 each.
// ---------------------------------------------------------------------------
__global__ __launch_bounds__(256) void proj_kernel(const float* __restrict__ x,
                                                   const unsigned short* __restrict__ wt,
                                                   unsigned short* __restrict__ qkv) {
    __shared__ unsigned short xs[128 * 72];   // row stride 72 shorts (pad 8 -> 2-way max)

    const int tid  = threadIdx.x;
    const int lane = tid & 63;
    const int wid  = tid >> 6;
    const int quad = lane >> 4;
    const int l15  = lane & 15;
    const int wm   = wid >> 1;     // 0..1
    const int wn   = wid & 1;      // 0..1
    const long blockM = (long)blockIdx.x * 128;

    f32x4 acc[4][6] = {};

    const int srow = tid >> 4;     // 0..15
    const int scol = tid & 15;     // float4 column
    const float* xbase = x + (blockM + srow) * 1024 + scol * 4;

    for (int k0 = 0; k0 < 1024; k0 += 64) {
        __syncthreads();
        // ---- stage x tile (128 x 64) fp32 -> bf16 LDS ----
#pragma unroll
        for (int p = 0; p < 8; p++) {
            const float4 v = *(const float4*)(xbase + (long)p * 16 * 1024 + k0);
            ushort4 bv;
            bv.x = f2bf(v.x); bv.y = f2bf(v.y); bv.z = f2bf(v.z); bv.w = f2bf(v.w);
            *(ushort4*)&xs[(srow + p * 16) * 72 + scol * 4] = bv;
        }
        __syncthreads();
        // ---- MFMA over this K slab ----
#pragma unroll
        for (int kk = 0; kk < 64; kk += 32) {
            s16x8 a[4], bf[6];
#pragma unroll
            for (int mt = 0; mt < 4; mt++)
                a[mt] = *(const s16x8*)&xs[(wm * 64 + mt * 16 + l15) * 72 + kk + quad * 8];
#pragma unroll
            for (int nt = 0; nt < 6; nt++)
                bf[nt] = *(const s16x8*)&wt[(long)(wn * 96 + nt * 16 + l15) * 1024 + k0 + kk + quad * 8];
#pragma unroll
            for (int mt = 0; mt < 4; mt++)
#pragma unroll
                for (int nt = 0; nt < 6; nt++)
                    acc[mt][nt] = __builtin_amdgcn_mfma_f32_16x16x32_bf16(a[mt], bf[nt], acc[mt][nt], 0, 0, 0);
        }
    }

    // ---- epilogue: store bf16 qkv ----
#pragma unroll
    for (int mt = 0; mt < 4; mt++)
#pragma unroll
        for (int nt = 0; nt < 6; nt++)
#pragma unroll
            for (int r = 0; r < 4; r++) {
                long row = blockM + wm * 64 + mt * 16 + quad * 4 + r;
                int  col = wn * 96 + nt * 16 + l15;
                qkv[row * 192 + col] = f2bf(acc[mt][nt][r]);
            }
}

// ---------------------------------------------------------------------------
// Kernel 2: causal flash attention. grid = 512 (b = idx>>1, half = idx&1).
// Each wave: 32 Q rows. Online softmax, s-tiles of 32.
// ---------------------------------------------------------------------------
__global__ __launch_bounds__(256) void attn_kernel(const unsigned short* __restrict__ qkv,
                                                   float* __restrict__ out) {
    __shared__ unsigned short Vt[64 * 264];    // V^T [h][s], row stride 264 (pad 8)
    __shared__ unsigned short Pl[4][16 * 56];  // per-wave P scratch, row stride 56 (112B, 16B-mult)

    const int tid  = threadIdx.x;
    const int lane = tid & 63;
    const int wid  = tid >> 6;
    const int quad = lane >> 4;
    const int l15  = lane & 15;
    const int b    = blockIdx.x >> 1;
    const int half = blockIdx.x & 1;

    const unsigned short* qb = qkv + (long)b * 256 * 192;

    // ---- stage V^T into LDS (only s-range this half needs) ----
    {
        const int vs = tid >> 2;            // 0..63
        const int vh = (tid & 3) * 16;      // h chunk
        const int npass = half ? 4 : 2;
        for (int p = 0; p < npass; p++) {
            int s = p * 64 + vs;
            const unsigned short* src = qb + s * 192 + 128 + vh;
            s16x8 v0 = *(const s16x8*)src;
            s16x8 v1 = *(const s16x8*)(src + 8);
#pragma unroll
            for (int i = 0; i < 8; i++) Vt[(vh + i) * 264 + s]     = (unsigned short)v0[i];
#pragma unroll
            for (int i = 0; i < 8; i++) Vt[(vh + 8 + i) * 264 + s] = (unsigned short)v1[i];
        }
    }
    __syncthreads();

    const int base = half * 128 + wid * 32;   // first Q row of this wave

    // ---- Q fragments (held in regs whole kernel) ----
    s16x8 qf[2][2];
#pragma unroll
    for (int mt = 0; mt < 2; mt++)
#pragma unroll
        for (int ks = 0; ks < 2; ks++)
            qf[mt][ks] = *(const s16x8*)(qb + (long)(base + mt * 16 + l15) * 192 + ks * 32 + quad * 8);

    f32x4 o[2][4] = {};
    float mr[2][4], lr[2][4];
#pragma unroll
    for (int mt = 0; mt < 2; mt++)
#pragma unroll
        for (int r = 0; r < 4; r++) { mr[mt][r] = -1e30f; lr[mt][r] = 0.0f; }

    const int nst = base / 32 + 1;
    for (int st = 0; st < nst; st++) {
        const int s0 = st * 32;
        s16x8 kf[2][2], vf[4];
#pragma unroll
        for (int sub = 0; sub < 2; sub++)
#pragma unroll
            for (int ks = 0; ks < 2; ks++)
                kf[sub][ks] = *(const s16x8*)(qb + (long)(s0 + sub * 16 + l15) * 192 + 64 + ks * 32 + quad * 8);
#pragma unroll
        for (int n = 0; n < 4; n++)
            vf[n] = *(const s16x8*)&Vt[(n * 16 + l15) * 264 + s0 + quad * 8];

#pragma unroll
        for (int mt = 0; mt < 2; mt++) {
            const int tmin = base + mt * 16;
            f32x4 S0 = {0.f, 0.f, 0.f, 0.f}, S1 = {0.f, 0.f, 0.f, 0.f};
            S0 = __builtin_amdgcn_mfma_f32_16x16x32_bf16(qf[mt][0], kf[0][0], S0, 0, 0, 0);
            S0 = __builtin_amdgcn_mfma_f32_16x16x32_bf16(qf[mt][1], kf[0][1], S0, 0, 0, 0);
            S1 = __builtin_amdgcn_mfma_f32_16x16x32_bf16(qf[mt][0], kf[1][0], S1, 0, 0, 0);
            S1 = __builtin_amdgcn_mfma_f32_16x16x32_bf16(qf[mt][1], kf[1][1], S1, 0, 0, 0);

            if (s0 + 31 > tmin) {   // diagonal tile: apply causal mask
#pragma unroll
                for (int r = 0; r < 4; r++) {
                    int t = tmin + quad * 4 + r;
                    if (s0 + l15 > t)      S0[r] = -1e30f;
                    if (s0 + 16 + l15 > t) S1[r] = -1e30f;
                }
            }

            float a4[4];
#pragma unroll
            for (int r = 0; r < 4; r++) {
                float rm = fmaxf(S0[r], S1[r]);
                rm = fmaxf(rm, __shfl_xor(rm, 1));
                rm = fmaxf(rm, __shfl_xor(rm, 2));
                rm = fmaxf(rm, __shfl_xor(rm, 4));
                rm = fmaxf(rm, __shfl_xor(rm, 8));
                float mn = fmaxf(mr[mt][r], rm);
                float al = exp2f((mr[mt][r] - mn) * 1.44269504f);
                mr[mt][r] = mn;
                float p0 = exp2f((S0[r] - mn) * 1.44269504f);
                float p1 = exp2f((S1[r] - mn) * 1.44269504f);
                float rs = p0 + p1;
                rs += __shfl_xor(rs, 1);
                rs += __shfl_xor(rs, 2);
                rs += __shfl_xor(rs, 4);
                rs += __shfl_xor(rs, 8);
                lr[mt][r] = al * lr[mt][r] + rs;
                a4[r] = al;
                Pl[wid][(quad * 4 + r) * 56 + l15]      = f2bf(p0);
                Pl[wid][(quad * 4 + r) * 56 + l15 + 16] = f2bf(p1);
            }
#pragma unroll
            for (int n = 0; n < 4; n++) {
                f32x4 t = o[mt][n];
#pragma unroll
                for (int r = 0; r < 4; r++) t[r] *= a4[r];
                o[mt][n] = t;
            }
            s16x8 pf = *(const s16x8*)&Pl[wid][l15 * 56 + quad * 8];
#pragma unroll
            for (int n = 0; n < 4; n++)
                o[mt][n] = __builtin_amdgcn_mfma_f32_16x16x32_bf16(pf, vf[n], o[mt][n], 0, 0, 0);
        }
    }

    // ---- normalize + store ----
#pragma unroll
    for (int mt = 0; mt < 2; mt++) {
        float inv[4];
#pragma unroll
        for (int r = 0; r < 4; r++) inv[r] = 1.0f / lr[mt][r];
#pragma unroll
        for (int n = 0; n < 4; n++)
#pragma unroll
            for (int r = 0; r < 4; r++) {
                long t = (long)b * 256 + base + mt * 16 + quad * 4 + r;
                out[t * 64 + n * 16 + l15] = o[mt][n][r] * inv[r];
            }
    }
}

// ---------------------------------------------------------------------------
extern "C" void kernel_launch(void* const* d_in, const int* in_sizes, int n_in,
                              void* d_out, int out_size, void* d_ws, size_t ws_size,
                              hipStream_t stream) {
    const float* x  = (const float*)d_in[0];
    const float* Wk = (const float*)d_in[1];
    const float* Wq = (const float*)d_in[2];
    const float* Wv = (const float*)d_in[3];
    float* out = (float*)d_out;

    unsigned short* wt  = (unsigned short*)d_ws;          // 192*1024 bf16
    unsigned short* qkv = wt + 192 * 1024;                // 65536*192 bf16

    prep_w<<<192, 256, 0, stream>>>(Wk, Wq, Wv, wt);
    proj_kernel<<<512, 256, 0, stream>>>(x, wt, qkv);
    attn_kernel<<<512, 256, 0, stream>>>(qkv, out);
}